// Round 2
// baseline (7077.853 us; speedup 1.0000x reference)
//
#include <hip/hip_runtime.h>
#include <math.h>

#define BB 32
#define EE 256
#define HH 512
#define VV 32000
#define TT 64
#define GO_ID 2
#define EOS_ID 3

#define NBL 500
#define NT  256

// ws layout (floats)
#define WS_HT0   0          // 512*32 transposed h, ping
#define WS_HT1   16384      // pong
#define WS_X     32768      // 32*256 current input embedding
#define WS_PART  40960      // 500*32 float4 partials
#define WS_M     104960     // 32 row maxes
#define WS_SINV  104992     // 32 reciprocal sums
#define WS_INT   105024     // flags[32], len[32]

// out layout (floats)
#define OUT_WO   65536000ULL
#define OUT_EMB  (OUT_WO + 2048ULL)
#define OUT_LEN  (OUT_EMB + 524288ULL)

__global__ __launch_bounds__(NT)
void k_init(const float* __restrict__ emb, float* __restrict__ ws)
{
    float* xbuf = ws + WS_X;
    int* toki  = (int*)(ws + WS_INT);
    int* flags = toki;
    int* lenac = toki + 32;
    xbuf[blockIdx.x*EE + threadIdx.x] = emb[GO_ID*EE + threadIdx.x];
    if (blockIdx.x == 0 && threadIdx.x < BB) { flags[threadIdx.x] = 0; lenac[threadIdx.x] = 0; }
}

// ---- GRU cell: h(t) = GRU(x(t), h(t-1)); grid = 128 blocks
__global__ __launch_bounds__(NT)
void k_gru(const float* __restrict__ Wih, const float* __restrict__ bih,
           const float* __restrict__ Whh, const float* __restrict__ bhh,
           const float* __restrict__ h0, float* __restrict__ ws, int t)
{
    const int blk = blockIdx.x, tid = threadIdx.x;
    float* hTprev = ws + (((t & 1) == 0) ? WS_HT1 : WS_HT0);
    float* hTcur  = ws + (((t & 1) == 0) ? WS_HT0 : WS_HT1);
    const float* xbuf = ws + WS_X;

    __shared__ float smem[1536];

    const int b    = tid & 31;
    const int q    = tid >> 5;
    const int k    = blk*4 + (q & 3);
    const int half = q >> 2;

    float s_ir = 0.f, s_iz = 0.f, s_in = 0.f;
    {
        const float4* x4 = (const float4*)xbuf + b*64;
        const float4* wr = (const float4*)Wih + (size_t)k*64;
        const float4* wz = (const float4*)Wih + (size_t)(HH + k)*64;
        const float4* wn = (const float4*)Wih + (size_t)(2*HH + k)*64;
        const int c0 = half*32, c1 = c0 + 32;
        for (int c4 = c0; c4 < c1; ++c4) {
            float4 xv = x4[c4];
            float4 a  = wr[c4];
            s_ir += a.x*xv.x + a.y*xv.y + a.z*xv.z + a.w*xv.w;
            float4 bz = wz[c4];
            s_iz += bz.x*xv.x + bz.y*xv.y + bz.z*xv.z + bz.w*xv.w;
            float4 cn = wn[c4];
            s_in += cn.x*xv.x + cn.y*xv.y + cn.z*xv.z + cn.w*xv.w;
        }
    }
    float s_hr = 0.f, s_hz = 0.f, s_hn = 0.f;
    {
        const float4* wr = (const float4*)Whh + (size_t)k*128;
        const float4* wz = (const float4*)Whh + (size_t)(HH + k)*128;
        const float4* wn = (const float4*)Whh + (size_t)(2*HH + k)*128;
        const int c0 = half*64, c1 = c0 + 64;
        if (t == 0) {
            const float4* h4 = (const float4*)h0 + b*128;
            for (int c4 = c0; c4 < c1; ++c4) {
                float4 hv = h4[c4];
                float4 a  = wr[c4];
                s_hr += a.x*hv.x + a.y*hv.y + a.z*hv.z + a.w*hv.w;
                float4 bz = wz[c4];
                s_hz += bz.x*hv.x + bz.y*hv.y + bz.z*hv.z + bz.w*hv.w;
                float4 cn = wn[c4];
                s_hn += cn.x*hv.x + cn.y*hv.y + cn.z*hv.z + cn.w*hv.w;
            }
        } else {
            const float4* h4 = (const float4*)hTprev;
            for (int c4 = c0; c4 < c1; ++c4) {
                float4 hv = h4[c4*32 + b];
                float4 a  = wr[c4];
                s_hr += a.x*hv.x + a.y*hv.y + a.z*hv.z + a.w*hv.w;
                float4 bz = wz[c4];
                s_hz += bz.x*hv.x + bz.y*hv.y + bz.z*hv.z + bz.w*hv.w;
                float4 cn = wn[c4];
                s_hn += cn.x*hv.x + cn.y*hv.y + cn.z*hv.z + cn.w*hv.w;
            }
        }
    }
    const int si = (q*32 + b)*6;
    smem[si+0] = s_ir; smem[si+1] = s_iz; smem[si+2] = s_in;
    smem[si+3] = s_hr; smem[si+4] = s_hz; smem[si+5] = s_hn;
    __syncthreads();
    if (q < 4) {
        const int i0 = (q*32 + b)*6, i1 = ((q+4)*32 + b)*6;
        float ir  = smem[i0+0] + smem[i1+0] + bih[k];
        float iz  = smem[i0+1] + smem[i1+1] + bih[HH + k];
        float inn = smem[i0+2] + smem[i1+2] + bih[2*HH + k];
        float hr  = smem[i0+3] + smem[i1+3] + bhh[k];
        float hz  = smem[i0+4] + smem[i1+4] + bhh[HH + k];
        float hn  = smem[i0+5] + smem[i1+5] + bhh[2*HH + k];
        float r = 1.f/(1.f + expf(-(ir + hr)));
        float z = 1.f/(1.f + expf(-(iz + hz)));
        float n = tanhf(inn + r*hn);
        float hp = (t == 0) ? h0[b*HH + k] : hTprev[(k>>2)*128 + b*4 + (k&3)];
        float hv = (1.f - z)*n + z*hp;
        hTcur[(k>>2)*128 + b*4 + (k&3)] = hv;
    }
}

// ---- logits + per-block softmax/argmax partials (+ normalize w_pro(t-1)); grid = 500
__global__ __launch_bounds__(NT)
void k_logits(const float* __restrict__ Wout, const float* __restrict__ bout,
              float* __restrict__ out, float* __restrict__ ws, int t)
{
    const int blk = blockIdx.x, tid = threadIdx.x;
    const float* hTcur = ws + (((t & 1) == 0) ? WS_HT0 : WS_HT1);
    float* part  = ws + WS_PART;
    const float* Mrow  = ws + WS_M;
    const float* SinvA = ws + WS_SINV;
    float* w_pro = out;

    __shared__ float smem[2080];

    if (t > 0) {
        float* wp = w_pro + (size_t)(t-1)*1024000 + blk*64;
        const int vl = tid & 63, bq = tid >> 6;
        #pragma unroll
        for (int r = 0; r < 8; ++r) {
            int b = r*4 + bq;
            size_t idx = (size_t)b*VV + vl;
            wp[idx] = expf(wp[idx] - Mrow[b]) * SinvA[b];
        }
    }

    const int b  = tid & 31;
    const int vg = tid >> 5;
    const int v0 = blk*64 + vg*8;
    float acc[8] = {0.f,0.f,0.f,0.f,0.f,0.f,0.f,0.f};
    const float4* hT4  = (const float4*)hTcur;
    const float4* wrow = (const float4*)Wout + (size_t)v0*128;
    for (int c4 = 0; c4 < 128; ++c4) {
        float4 hv = hT4[c4*32 + b];
        #pragma unroll
        for (int i = 0; i < 8; ++i) {
            float4 wv = wrow[(size_t)i*128 + c4];
            acc[i] += wv.x*hv.x + wv.y*hv.y + wv.z*hv.z + wv.w*hv.w;
        }
    }
    __syncthreads();
    #pragma unroll
    for (int i = 0; i < 8; ++i)
        smem[b*65 + vg*8 + i] = acc[i] + bout[v0 + i];
    __syncthreads();
    {   // coalesced store of raw logits
        float* wp = w_pro + (size_t)t*1024000 + blk*64;
        const int vl = tid & 63, bq = tid >> 6;
        #pragma unroll
        for (int r = 0; r < 8; ++r) {
            int b2 = r*4 + bq;
            wp[(size_t)b2*VV + vl] = smem[b2*65 + vl];
        }
    }
    {   // per-block partial max / sumexp / argmax(v>=2)
        const int rb = tid >> 3, l = tid & 7;
        float m = -INFINITY, s = 0.f, av = -INFINITY; int ai = 0;
        for (int j = l; j < 64; j += 8) {
            float val = smem[rb*65 + j];
            if (val > m) { s = s*expf(m - val) + 1.f; m = val; }
            else         { s += expf(val - m); }
            int vglob = blk*64 + j;
            if (vglob >= 2 && val > av) { av = val; ai = vglob; }
        }
        for (int d = 1; d < 8; d <<= 1) {
            float m2  = __shfl_xor(m, d);
            float s2  = __shfl_xor(s, d);
            float av2 = __shfl_xor(av, d);
            int   ai2 = __shfl_xor(ai, d);
            float mn = fmaxf(m, m2);
            s = s*expf(m - mn) + s2*expf(m2 - mn); m = mn;
            if (av2 > av || (av2 == av && ai2 < ai)) { av = av2; ai = ai2; }
        }
        if (l == 0)
            ((float4*)part)[blk*32 + rb] = make_float4(m, s, av, __int_as_float(ai));
    }
}

// ---- final softmax reduce per row, token select, outputs, next x; grid = 32
__global__ __launch_bounds__(NT)
void k_reduce(const float* __restrict__ emb, float* __restrict__ out,
              float* __restrict__ ws, int t)
{
    const int b = blockIdx.x, tid = threadIdx.x;
    const float* part = ws + WS_PART;
    float* Mrow  = ws + WS_M;
    float* SinvA = ws + WS_SINV;
    int*   flags = (int*)(ws + WS_INT);
    int*   lenac = flags + 32;
    float* xbuf  = ws + WS_X;

    float* w_o    = out + OUT_WO;
    float* emb_sq = out + OUT_EMB;
    float* len_o  = out + OUT_LEN;

    __shared__ float smem[32];

    float m = -INFINITY, s = 0.f, av = -INFINITY; int ai = 0;
    for (int j = tid; j < NBL; j += NT) {
        float4 p = ((const float4*)part)[j*32 + b];
        float mn = fmaxf(m, p.x);
        s = s*expf(m - mn) + p.y*expf(p.x - mn); m = mn;
        int aij = __float_as_int(p.w);
        if (p.z > av || (p.z == av && aij < ai)) { av = p.z; ai = aij; }
    }
    for (int d = 1; d < 64; d <<= 1) {
        float m2  = __shfl_xor(m, d);
        float s2  = __shfl_xor(s, d);
        float av2 = __shfl_xor(av, d);
        int   ai2 = __shfl_xor(ai, d);
        float mn = fmaxf(m, m2);
        s = s*expf(m - mn) + s2*expf(m2 - mn); m = mn;
        if (av2 > av || (av2 == av && ai2 < ai)) { av = av2; ai = ai2; }
    }
    const int wid = tid >> 6, lane = tid & 63;
    if (lane == 0) {
        smem[wid*4+0] = m; smem[wid*4+1] = s;
        smem[wid*4+2] = av; smem[wid*4+3] = __int_as_float(ai);
    }
    __syncthreads();
    if (tid == 0) {
        float M = smem[0], S = smem[1], AV = smem[2];
        int AI = __float_as_int(smem[3]);
        for (int w2 = 1; w2 < 4; ++w2) {
            float m2 = smem[w2*4], s2 = smem[w2*4+1], av2 = smem[w2*4+2];
            int ai2 = __float_as_int(smem[w2*4+3]);
            float mn = fmaxf(M, m2);
            S = S*expf(M - mn) + s2*expf(m2 - mn); M = mn;
            if (av2 > AV || (av2 == AV && ai2 < AI)) { AV = av2; AI = ai2; }
        }
        Mrow[b] = M; SinvA[b] = 1.f/S;
        int fl = flags[b];
        int alive = fl ? 0 : 1;
        w_o[t*BB + b] = alive ? (float)AI : 0.f;
        flags[b] = fl | (AI == EOS_ID ? 1 : 0);
        lenac[b] += alive;
        if (t == TT-1) len_o[b] = (float)lenac[b];
        smem[16] = __int_as_float(AI);
        smem[17] = (float)alive;
    }
    __syncthreads();
    const int tok = __float_as_int(smem[16]);
    const float alive = smem[17];
    float e = emb[(size_t)tok*EE + tid];
    xbuf[b*EE + tid] = e;                                   // unmasked feedback
    emb_sq[(size_t)t*8192 + b*EE + tid] = alive * e;        // masked output
}

// ---- normalize w_pro for t = 63; grid = 500
__global__ __launch_bounds__(NT)
void k_norm_last(float* __restrict__ out, float* __restrict__ ws)
{
    const int blk = blockIdx.x, tid = threadIdx.x;
    const float* Mrow  = ws + WS_M;
    const float* SinvA = ws + WS_SINV;
    float* wp = out + (size_t)(TT-1)*1024000 + blk*64;
    const int vl = tid & 63, bq = tid >> 6;
    #pragma unroll
    for (int r = 0; r < 8; ++r) {
        int b = r*4 + bq;
        size_t idx = (size_t)b*VV + vl;
        wp[idx] = expf(wp[idx] - Mrow[b]) * SinvA[b];
    }
}

extern "C" void kernel_launch(void* const* d_in, const int* in_sizes, int n_in,
                              void* d_out, int out_size, void* d_ws, size_t ws_size,
                              hipStream_t stream)
{
    const float* emb  = (const float*)d_in[0];
    const float* Wih  = (const float*)d_in[1];
    const float* bih  = (const float*)d_in[2];
    const float* Whh  = (const float*)d_in[3];
    const float* bhh  = (const float*)d_in[4];
    const float* Wout = (const float*)d_in[5];
    const float* bout = (const float*)d_in[6];
    const float* h0   = (const float*)d_in[7];
    float* out = (float*)d_out;
    float* ws  = (float*)d_ws;

    hipLaunchKernelGGL(k_init, dim3(BB), dim3(NT), 0, stream, emb, ws);
    for (int t = 0; t < TT; ++t) {
        hipLaunchKernelGGL(k_gru,    dim3(128), dim3(NT), 0, stream, Wih, bih, Whh, bhh, h0, ws, t);
        hipLaunchKernelGGL(k_logits, dim3(NBL), dim3(NT), 0, stream, Wout, bout, out, ws, t);
        hipLaunchKernelGGL(k_reduce, dim3(BB),  dim3(NT), 0, stream, emb, out, ws, t);
    }
    hipLaunchKernelGGL(k_norm_last, dim3(NBL), dim3(NT), 0, stream, out, ws);
}